// Round 2
// baseline (831.175 us; speedup 1.0000x reference)
//
#include <hip/hip_runtime.h>

#define BS   1024
#define DD   128

typedef __attribute__((ext_vector_type(8))) short  short8;
typedef __attribute__((ext_vector_type(4))) float  f32x4;
typedef __attribute__((ext_vector_type(4))) unsigned short us4;

// ---------------------------------------------------------------------------
// Fused kernel: per wg = (block b, i-tile of 128 rows).
// No pass1 / no workspace: fp32 -> bf16 conversion, sq, and the transposed
// XjT tile are all produced in-kernel per j-tile (conversion is redundant 8x
// across the block's i-tile wgs, but they share the XCD L2 and the main
// kernel has idle VALU/memory headroom: MfmaUtil 33%, HBM 15%).
//
// LDS (51.2 KB + 256 B) -> 3 wg/CU:
//   XjRM [64][128] bf16, 16B-chunk XOR-swizzled per row     (16 KB)
//   XjT  [128][64] bf16, 16B-chunk XOR-swizzled per d-row   (16 KB)
//   Pm   [128][72] bf16                                     (18 KB)
//   csqj [64] f32 (sq_j * log2e/25.6)
// ---------------------------------------------------------------------------
__global__ __launch_bounds__(256, 3)
void block_attn_fused(const float* __restrict__ x, float* __restrict__ out) {
    __shared__ __align__(16) unsigned short lds[25600];
    __shared__ __align__(16) float csqj[64];
    unsigned short* XjRM = lds;           // elems 0..8191
    unsigned short* XjT  = lds + 8192;    // elems 8192..16383
    unsigned short* Pm   = lds + 16384;   // elems 16384..25599

    const int tid  = threadIdx.x;
    const int lane = tid & 63;
    const int wv   = tid >> 6;
    const int r16  = lane & 15;
    const int q    = lane >> 4;
    const int sw   = r16 & 7;             // frag-read swizzle key
    const int tr   = tid >> 4;            // 0..15 (j-row group for conversion)
    const int tc   = tid & 15;            // 0..15 (d-chunk for conversion)

    const unsigned w = blockIdx.x;
    const int b  = ((w >> 6) << 3) + (w & 7);   // 8 i-tiles of b on one XCD
    const int ti = (w >> 3) & 7;
    const int i0 = b * BS + ti * 128;

    // log2(e) folded into the 1/25.6 scales -> single v_exp_f32 via
    // __builtin_amdgcn_exp2f (NOTE: __exp2f does not exist device-side).
    const float c1 = 0.056355275f;        // log2(e)/25.6
    const float c2 = 0.112710550f;        // 2*log2(e)/25.6

    // ---- Xi fragments: convert directly from global fp32, once per wg ----
    // lane(r16,q) of wave wv loads chunks {q,4+q,8+q,12+q} (8 floats each) of
    // rows i0 + wv*32 + im*16 + r16; sq reduced over the q-group via shfl.
    short8 xi[2][4];
    float ci[2];
    #pragma unroll
    for (int im = 0; im < 2; ++im) {
        const float* src = x + (size_t)(i0 + wv * 32 + im * 16 + r16) * DD;
        float ssq = 0.f;
        #pragma unroll
        for (int kk = 0; kk < 4; ++kk) {
            const int c = kk * 4 + q;
            const float4 f0 = *(const float4*)(src + c * 8);
            const float4 f1 = *(const float4*)(src + c * 8 + 4);
            const float v[8] = {f0.x, f0.y, f0.z, f0.w, f1.x, f1.y, f1.z, f1.w};
            short8 pk;
            #pragma unroll
            for (int e = 0; e < 8; ++e) {
                const unsigned u = __float_as_uint(v[e]) + 0x8000u;
                const float ft = __uint_as_float(u & 0xFFFF0000u);
                ssq += ft * ft;
                pk[e] = (short)(u >> 16);
            }
            xi[im][kk] = pk;
        }
        ssq += __shfl_xor(ssq, 16);
        ssq += __shfl_xor(ssq, 32);
        ci[im] = ssq * c1;
    }

    f32x4 acc_o[2][8];
    #pragma unroll
    for (int im = 0; im < 2; ++im)
        #pragma unroll
        for (int nt = 0; nt < 8; ++nt)
            acc_o[im][nt] = (f32x4){0.f, 0.f, 0.f, 0.f};

    for (int jt = 0; jt < 16; ++jt) {
        // ---- issue Xj fp32 loads BEFORE the barrier: latency hides under
        //      the barrier wait (loads touch no LDS; safe across s_barrier) ----
        const float* srcj = x + (size_t)(b * BS + jt * 64 + tr * 4) * DD + tc * 8;
        float4 f[4][2];
        #pragma unroll
        for (int rr = 0; rr < 4; ++rr) {
            f[rr][0] = *(const float4*)(srcj + (size_t)rr * DD);
            f[rr][1] = *(const float4*)(srcj + (size_t)rr * DD + 4);
        }
        __syncthreads();   // prev-iter XjRM/XjT reads complete

        // ---- convert rows tr*4+rr: XjRM (swizzled b128) + sq_j + packed bf16 ----
        unsigned bfp[4][4];   // [rr][pair]: bf16 pair dwords (cols tc*8 .. tc*8+7)
        #pragma unroll
        for (int rr = 0; rr < 4; ++rr) {
            const float v[8] = {f[rr][0].x, f[rr][0].y, f[rr][0].z, f[rr][0].w,
                                f[rr][1].x, f[rr][1].y, f[rr][1].z, f[rr][1].w};
            float s = 0.f;
            #pragma unroll
            for (int p = 0; p < 4; ++p) {
                const unsigned u0 = __float_as_uint(v[2 * p]) + 0x8000u;
                const unsigned u1 = __float_as_uint(v[2 * p + 1]) + 0x8000u;
                const float t0 = __uint_as_float(u0 & 0xFFFF0000u);
                const float t1 = __uint_as_float(u1 & 0xFFFF0000u);
                s += t0 * t0 + t1 * t1;
                bfp[rr][p] = (u0 >> 16) | (u1 & 0xFFFF0000u);
            }
            const int row = tr * 4 + rr;
            *(uint4*)&XjRM[row * 128 + ((tc ^ (row & 7)) << 3)] =
                make_uint4(bfp[rr][0], bfp[rr][1], bfp[rr][2], bfp[rr][3]);
            s += __shfl_xor(s, 1);
            s += __shfl_xor(s, 2);
            s += __shfl_xor(s, 4);
            s += __shfl_xor(s, 8);
            if (tc == rr) csqj[row] = s * c1;
        }

        // ---- XjT columns: thread owns the 4x8 tile (j=tr*4.., d=tc*8..).
        //      e ^= tc&7 spreads writes over 16 LDS slots (4-way, not 16-way).
        //      Layout matches reader: chunk jg of row d stored at jg^(d&7). ----
        #pragma unroll
        for (int ee = 0; ee < 8; ++ee) {
            const int e = ee ^ (tc & 7);
            const int p = e >> 1;
            const unsigned sh = (e & 1) << 4;
            const unsigned h0 = (bfp[0][p] >> sh) & 0xFFFFu;
            const unsigned h1 = (bfp[1][p] >> sh) & 0xFFFFu;
            const unsigned h2 = (bfp[2][p] >> sh) & 0xFFFFu;
            const unsigned h3 = (bfp[3][p] >> sh) & 0xFFFFu;
            const int d = tc * 8 + e;     // d&7 == e
            *(uint2*)&XjT[d * 64 + (((tr >> 1) ^ e) << 3) + ((tr & 1) << 2)] =
                make_uint2(h0 | (h1 << 16), h2 | (h3 << 16));
        }
        __syncthreads();   // staging visible

        // ---- S^T: A = Xj rows (LDS), B = Xi rows (regs); C row=j, col=i ----
        #pragma unroll
        for (int jn = 0; jn < 4; ++jn) {
            f32x4 a0 = (f32x4){0.f, 0.f, 0.f, 0.f};
            f32x4 a1 = (f32x4){0.f, 0.f, 0.f, 0.f};
            #pragma unroll
            for (int kk = 0; kk < 4; ++kk) {
                const short8 xj = *(const short8*)&XjRM[(jn * 16 + r16) * 128 +
                                                        (((kk * 4 + q) ^ sw) << 3)];
                a0 = __builtin_amdgcn_mfma_f32_16x16x32_bf16(xj, xi[0][kk], a0, 0, 0, 0);
                a1 = __builtin_amdgcn_mfma_f32_16x16x32_bf16(xj, xi[1][kk], a1, 0, 0, 0);
            }
            const f32x4 sj = *(const f32x4*)&csqj[jn * 16 + q * 4];
            #pragma unroll
            for (int im = 0; im < 2; ++im) {
                const f32x4 a = im ? a1 : a0;
                const float cii = ci[im];
                us4 hv;
                #pragma unroll
                for (int rg = 0; rg < 4; ++rg) {
                    float arg = fmaf(a[rg], c2, -(sj[rg] + cii));
                    arg = fminf(arg, 0.f);
                    const float wval = __builtin_amdgcn_exp2f(arg);
                    hv[rg] = (unsigned short)((__float_as_uint(wval) + 0x8000u) >> 16);
                }
                // P[i = wv*32+im*16+r16][j = jn*16+q*4 .. +3]
                *(us4*)&Pm[(wv * 32 + im * 16 + r16) * 72 + jn * 16 + q * 4] = hv;
            }
        }

        // ---- O += P . Xj : A = own P rows, B = XjT (no barrier needed) ----
        #pragma unroll
        for (int kk = 0; kk < 2; ++kk) {
            const short8 pf0 = *(const short8*)&Pm[(wv * 32 + r16) * 72 + kk * 32 + q * 8];
            const short8 pf1 = *(const short8*)&Pm[(wv * 32 + 16 + r16) * 72 + kk * 32 + q * 8];
            #pragma unroll
            for (int nt = 0; nt < 8; ++nt) {
                const short8 bf = *(const short8*)&XjT[(nt * 16 + r16) * 64 +
                                                       (((kk * 4 + q) ^ sw) << 3)];
                acc_o[0][nt] = __builtin_amdgcn_mfma_f32_16x16x32_bf16(pf0, bf, acc_o[0][nt], 0, 0, 0);
                acc_o[1][nt] = __builtin_amdgcn_mfma_f32_16x16x32_bf16(pf1, bf, acc_o[1][nt], 0, 0, 0);
            }
        }
    }

    // ---- epilogue ----
    const float sc = 1.0f / 1024.0f;
    #pragma unroll
    for (int im = 0; im < 2; ++im)
        #pragma unroll
        for (int nt = 0; nt < 8; ++nt)
            #pragma unroll
            for (int rg = 0; rg < 4; ++rg) {
                const int row = i0 + wv * 32 + im * 16 + q * 4 + rg;
                out[(size_t)row * DD + nt * 16 + r16] = acc_o[im][nt][rg] * sc;
            }
}

extern "C" void kernel_launch(void* const* d_in, const int* in_sizes, int n_in,
                              void* d_out, int out_size, void* d_ws, size_t ws_size,
                              hipStream_t stream) {
    (void)in_sizes; (void)n_in; (void)out_size; (void)d_ws; (void)ws_size;
    const float* x = (const float*)d_in[0];
    float* out = (float*)d_out;
    block_attn_fused<<<dim3(2048), dim3(256), 0, stream>>>(x, out);
}

// Round 3
// 381.573 us; speedup vs baseline: 2.1783x; 2.1783x over previous
//
#include <hip/hip_runtime.h>

#define BS   1024
#define DD   128

typedef __attribute__((ext_vector_type(8))) short  short8;
typedef __attribute__((ext_vector_type(4))) float  f32x4;
typedef __attribute__((ext_vector_type(4))) unsigned short us4;

#define AS1 __attribute__((address_space(1)))
#define AS3 __attribute__((address_space(3)))

static __device__ __forceinline__ void gl_lds16(const void* g, void* l) {
    __builtin_amdgcn_global_load_lds((const AS1 unsigned int*)g,
                                     (AS3 unsigned int*)l, 16, 0, 0);
}

// ---------------------------------------------------------------------------
// Pass 1 (rewritten, LDS-free): fp32 X ->
//   (a) row-major bf16 xrm, XOR-8 16B-chunk swizzle per row
//   (b) per-block transposed xt  [block][slice][d 0..127][swz j-chunk]
//   (c) sq[row] * (1/25.6)
// Thread owns a 4-row x 8-d tile: the XT columns are extracted from the
// packed bf16 pair-dwords in registers (no LDS transpose, no barrier).
// R0's LDS-based pass1 ran at 1.4 TB/s (185 us); this is pure streaming.
// ---------------------------------------------------------------------------
__global__ __launch_bounds__(256, 4)
void pass1_convert(const float* __restrict__ x, unsigned short* __restrict__ xrm,
                   unsigned short* __restrict__ xt, float* __restrict__ sqg) {
    const int t  = threadIdx.x;
    const int tr = t >> 4;                 // j-row group: rows tr*4 .. tr*4+3
    const int tc = t & 15;                 // d-chunk: d = tc*8 .. tc*8+7
    const int b  = blockIdx.x >> 4;
    const int s  = blockIdx.x & 15;
    const int lrow0 = tr * 4;              // local row in 64-row slice
    const int grow0 = b * BS + s * 64 + lrow0;

    // ---- load 4 rows x 8 floats (issue all 8 loads up front for MLP) ----
    const float* src = x + (size_t)grow0 * DD + tc * 8;
    float4 f[4][2];
    #pragma unroll
    for (int rr = 0; rr < 4; ++rr) {
        f[rr][0] = *(const float4*)(src + (size_t)rr * DD);
        f[rr][1] = *(const float4*)(src + (size_t)rr * DD + 4);
    }

    // ---- convert, write xrm chunks, reduce+write sq ----
    unsigned bfp[4][4];   // [rr][pair]: bf16 pair dwords for d = tc*8+2p, +1
    #pragma unroll
    for (int rr = 0; rr < 4; ++rr) {
        const float v[8] = {f[rr][0].x, f[rr][0].y, f[rr][0].z, f[rr][0].w,
                            f[rr][1].x, f[rr][1].y, f[rr][1].z, f[rr][1].w};
        float ssq = 0.f;
        #pragma unroll
        for (int p = 0; p < 4; ++p) {
            const unsigned u0 = __float_as_uint(v[2 * p]) + 0x8000u;
            const unsigned u1 = __float_as_uint(v[2 * p + 1]) + 0x8000u;
            const float t0 = __uint_as_float(u0 & 0xFFFF0000u);
            const float t1 = __uint_as_float(u1 & 0xFFFF0000u);
            ssq += t0 * t0 + t1 * t1;
            bfp[rr][p] = (u0 >> 16) | (u1 & 0xFFFF0000u);
        }
        const int lrow = lrow0 + rr;
        const int grow = grow0 + rr;
        // xrm: chunk tc of row grow, stored at position tc ^ (row&7)
        *(uint4*)((char*)xrm + (size_t)grow * 256 + ((tc ^ (lrow & 7)) << 4)) =
            make_uint4(bfp[rr][0], bfp[rr][1], bfp[rr][2], bfp[rr][3]);
        // sq: reduce over the 16 tc lanes (d-chunks) of this row
        ssq += __shfl_xor(ssq, 1);
        ssq += __shfl_xor(ssq, 2);
        ssq += __shfl_xor(ssq, 4);
        ssq += __shfl_xor(ssq, 8);
        if (tc == rr) sqg[grow] = ssq * 0.0390625f;   // sq / 25.6
    }

    // ---- xt: in-register transpose. Row d of the slice = 64 j x bf16
    //      (128 B), chunk jg (j = jg*8..+7) stored at jg ^ (d&7).
    //      This thread supplies j = tr*4..+3 (half of chunk jg=tr>>1),
    //      at short offset (tr&1)*4 within the chunk. ----
    unsigned short* xts = xt + (size_t)(b * 16 + s) * 8192;   // 16384 B slice
    const int jg = tr >> 1;
    const int halfoff = (tr & 1) << 2;    // shorts
    #pragma unroll
    for (int e = 0; e < 8; ++e) {
        const int p = e >> 1;
        const unsigned sh = (e & 1) << 4;
        const unsigned h0 = (bfp[0][p] >> sh) & 0xFFFFu;
        const unsigned h1 = (bfp[1][p] >> sh) & 0xFFFFu;
        const unsigned h2 = (bfp[2][p] >> sh) & 0xFFFFu;
        const unsigned h3 = (bfp[3][p] >> sh) & 0xFFFFu;
        const int d = tc * 8 + e;         // d&7 == e
        *(uint2*)&xts[d * 64 + ((jg ^ e) << 3) + halfoff] =
            make_uint2(h0 | (h1 << 16), h2 | (h3 << 16));
    }
}

// ---------------------------------------------------------------------------
// Main kernel (UNCHANGED from the proven 384us version, R0):
// per wg = (block b, i-tile 128 rows).
// LDS: [0..16383]B XjRM (64x256B swz) | [16384..32767]B XjT (128x128B swz)
//      (both regions = Xi staging 32KB at init) | [32768..51199]B P (128x144B)
// ---------------------------------------------------------------------------
__global__ __launch_bounds__(256, 3)
void block_attn_mx(const unsigned short* __restrict__ xrm,
                   const unsigned short* __restrict__ xt,
                   const float* __restrict__ sqg, float* __restrict__ out) {
    __shared__ __align__(16) unsigned short lds[25600];
    unsigned short* XjT = lds + 8192;    // elem index (byte 16384)
    unsigned short* Pm  = lds + 16384;   // byte 32768, stride 72 elems (144 B)

    const int tid  = threadIdx.x;
    const int lane = tid & 63;
    const int wv   = tid >> 6;
    const int r16  = lane & 15;
    const int q    = lane >> 4;
    const int sw   = r16 & 7;            // frag-read swizzle key

    const unsigned w = blockIdx.x;
    const int b  = ((w >> 6) << 3) + (w & 7);   // all 8 tiles of b on one XCD, adjacent
    const int ti = (w >> 3) & 7;
    const int i0 = b * BS + ti * 128;

    const float c2 = 0.078125f;          // 2/25.6

    // ---- stage Xi (32 KB) via global_load_lds, identity copy ----
    {
        const char* srcb = (const char*)xrm + (size_t)i0 * 256;
        #pragma unroll
        for (int k = 0; k < 8; ++k) {
            const int off = (wv * 8 + k) * 1024;
            gl_lds16(srcb + off + lane * 16, (void*)((char*)lds + off));
        }
    }
    __syncthreads();

    // Xi B-frags (persist in registers): B[n=i][k=d]
    short8 xi[2][4];
    #pragma unroll
    for (int im = 0; im < 2; ++im)
        #pragma unroll
        for (int kk = 0; kk < 4; ++kk)
            xi[im][kk] = *(const short8*)&lds[(wv * 32 + im * 16 + r16) * 128 +
                                             (((kk * 4 + q) ^ sw) << 3)];
    const float ci0 = sqg[i0 + wv * 32 + r16];
    const float ci1 = sqg[i0 + wv * 32 + 16 + r16];

    f32x4 acc_o[2][8];
    #pragma unroll
    for (int im = 0; im < 2; ++im)
        #pragma unroll
        for (int nt = 0; nt < 8; ++nt)
            acc_o[im][nt] = (f32x4){0.f, 0.f, 0.f, 0.f};

    for (int jt = 0; jt < 16; ++jt) {
        __syncthreads();   // previous buffers (or Xi frag reads) complete
        // ---- stage XjRM (waves 0,1) + XjT (waves 2,3), 8 x 1KB each ----
        if (wv < 2) {
            const char* srcb = (const char*)xrm + (size_t)(b * BS + jt * 64) * 256;
            #pragma unroll
            for (int k = 0; k < 8; ++k) {
                const int off = (wv * 8 + k) * 1024;
                gl_lds16(srcb + off + lane * 16, (void*)((char*)lds + off));
            }
        } else {
            const char* srcb = (const char*)xt + (size_t)(b * 16 + jt) * 16384;
            #pragma unroll
            for (int k = 0; k < 8; ++k) {
                const int off = ((wv - 2) * 8 + k) * 1024;
                gl_lds16(srcb + off + lane * 16, (void*)((char*)lds + 16384 + off));
            }
        }
        __syncthreads();   // staging complete (barrier drains vmcnt)

        // ---- S^T tile-by-tile: A = Xj rows (LDS), B = Xi rows (regs) ----
        // C row = j-local = q*4+rg, col = i-local = r16  -> P store contiguous b64
        #pragma unroll
        for (int jn = 0; jn < 4; ++jn) {
            f32x4 a0 = (f32x4){0.f, 0.f, 0.f, 0.f};
            f32x4 a1 = (f32x4){0.f, 0.f, 0.f, 0.f};
            #pragma unroll
            for (int kk = 0; kk < 4; ++kk) {
                const short8 xj = *(const short8*)&lds[(jn * 16 + r16) * 128 +
                                                       (((kk * 4 + q) ^ sw) << 3)];
                a0 = __builtin_amdgcn_mfma_f32_16x16x32_bf16(xj, xi[0][kk], a0, 0, 0, 0);
                a1 = __builtin_amdgcn_mfma_f32_16x16x32_bf16(xj, xi[1][kk], a1, 0, 0, 0);
            }
            const f32x4 sj = *(const f32x4*)&sqg[b * BS + jt * 64 + jn * 16 + q * 4];
            #pragma unroll
            for (int im = 0; im < 2; ++im) {
                const f32x4 a = im ? a1 : a0;
                const float ci = im ? ci1 : ci0;
                us4 hv;
                #pragma unroll
                for (int rg = 0; rg < 4; ++rg) {
                    float arg = fmaf(a[rg], c2, -(sj[rg] + ci));
                    arg = fminf(arg, 0.f);
                    hv[rg] = (unsigned short)((__float_as_uint(__expf(arg)) + 0x8000u) >> 16);
                }
                // P[i = wv*32+im*16+r16][j = jn*16+q*4 .. +3]
                *(us4*)&Pm[(wv * 32 + im * 16 + r16) * 72 + jn * 16 + q * 4] = hv;
            }
        }

        // ---- O += P · Xj : A = own P rows, B = XjT (no barrier needed) ----
        #pragma unroll
        for (int kk = 0; kk < 2; ++kk) {
            const short8 pf0 = *(const short8*)&Pm[(wv * 32 + r16) * 72 + kk * 32 + q * 8];
            const short8 pf1 = *(const short8*)&Pm[(wv * 32 + 16 + r16) * 72 + kk * 32 + q * 8];
            #pragma unroll
            for (int nt = 0; nt < 8; ++nt) {
                const short8 bf = *(const short8*)&XjT[(nt * 16 + r16) * 64 +
                                                       (((kk * 4 + q) ^ sw) << 3)];
                acc_o[0][nt] = __builtin_amdgcn_mfma_f32_16x16x32_bf16(pf0, bf, acc_o[0][nt], 0, 0, 0);
                acc_o[1][nt] = __builtin_amdgcn_mfma_f32_16x16x32_bf16(pf1, bf, acc_o[1][nt], 0, 0, 0);
            }
        }
    }

    // ---- epilogue ----
    const float sc = 1.0f / 1024.0f;
    #pragma unroll
    for (int im = 0; im < 2; ++im)
        #pragma unroll
        for (int nt = 0; nt < 8; ++nt)
            #pragma unroll
            for (int rg = 0; rg < 4; ++rg) {
                const int row = i0 + wv * 32 + im * 16 + q * 4 + rg;
                out[(size_t)row * DD + nt * 16 + r16] = acc_o[im][nt][rg] * sc;
            }
}

// ---------------------------------------------------------------------------
// Fallback (fully fused, passes at 831us): used only if ws_size is too small.
// ---------------------------------------------------------------------------
__global__ __launch_bounds__(256, 3)
void block_attn_fused(const float* __restrict__ x, float* __restrict__ out) {
    __shared__ __align__(16) unsigned short lds[25600];
    __shared__ __align__(16) float csqj[64];
    unsigned short* XjRM = lds;
    unsigned short* XjT  = lds + 8192;
    unsigned short* Pm   = lds + 16384;

    const int tid  = threadIdx.x;
    const int lane = tid & 63;
    const int wv   = tid >> 6;
    const int r16  = lane & 15;
    const int q    = lane >> 4;
    const int sw   = r16 & 7;
    const int tr   = tid >> 4;
    const int tc   = tid & 15;

    const unsigned w = blockIdx.x;
    const int b  = ((w >> 6) << 3) + (w & 7);
    const int ti = (w >> 3) & 7;
    const int i0 = b * BS + ti * 128;

    const float c1 = 0.056355275f;
    const float c2 = 0.112710550f;

    short8 xi[2][4];
    float ci[2];
    #pragma unroll
    for (int im = 0; im < 2; ++im) {
        const float* src = x + (size_t)(i0 + wv * 32 + im * 16 + r16) * DD;
        float ssq = 0.f;
        #pragma unroll
        for (int kk = 0; kk < 4; ++kk) {
            const int c = kk * 4 + q;
            const float4 f0 = *(const float4*)(src + c * 8);
            const float4 f1 = *(const float4*)(src + c * 8 + 4);
            const float v[8] = {f0.x, f0.y, f0.z, f0.w, f1.x, f1.y, f1.z, f1.w};
            short8 pk;
            #pragma unroll
            for (int e = 0; e < 8; ++e) {
                const unsigned u = __float_as_uint(v[e]) + 0x8000u;
                const float ft = __uint_as_float(u & 0xFFFF0000u);
                ssq += ft * ft;
                pk[e] = (short)(u >> 16);
            }
            xi[im][kk] = pk;
        }
        ssq += __shfl_xor(ssq, 16);
        ssq += __shfl_xor(ssq, 32);
        ci[im] = ssq * c1;
    }

    f32x4 acc_o[2][8];
    #pragma unroll
    for (int im = 0; im < 2; ++im)
        #pragma unroll
        for (int nt = 0; nt < 8; ++nt)
            acc_o[im][nt] = (f32x4){0.f, 0.f, 0.f, 0.f};

    for (int jt = 0; jt < 16; ++jt) {
        const float* srcj = x + (size_t)(b * BS + jt * 64 + tr * 4) * DD + tc * 8;
        float4 f[4][2];
        #pragma unroll
        for (int rr = 0; rr < 4; ++rr) {
            f[rr][0] = *(const float4*)(srcj + (size_t)rr * DD);
            f[rr][1] = *(const float4*)(srcj + (size_t)rr * DD + 4);
        }
        __syncthreads();

        unsigned bfp[4][4];
        #pragma unroll
        for (int rr = 0; rr < 4; ++rr) {
            const float v[8] = {f[rr][0].x, f[rr][0].y, f[rr][0].z, f[rr][0].w,
                                f[rr][1].x, f[rr][1].y, f[rr][1].z, f[rr][1].w};
            float s = 0.f;
            #pragma unroll
            for (int p = 0; p < 4; ++p) {
                const unsigned u0 = __float_as_uint(v[2 * p]) + 0x8000u;
                const unsigned u1 = __float_as_uint(v[2 * p + 1]) + 0x8000u;
                const float t0 = __uint_as_float(u0 & 0xFFFF0000u);
                const float t1 = __uint_as_float(u1 & 0xFFFF0000u);
                s += t0 * t0 + t1 * t1;
                bfp[rr][p] = (u0 >> 16) | (u1 & 0xFFFF0000u);
            }
            const int row = tr * 4 + rr;
            *(uint4*)&XjRM[row * 128 + ((tc ^ (row & 7)) << 3)] =
                make_uint4(bfp[rr][0], bfp[rr][1], bfp[rr][2], bfp[rr][3]);
            s += __shfl_xor(s, 1);
            s += __shfl_xor(s, 2);
            s += __shfl_xor(s, 4);
            s += __shfl_xor(s, 8);
            if (tc == rr) csqj[row] = s * c1;
        }

        #pragma unroll
        for (int ee = 0; ee < 8; ++ee) {
            const int e = ee ^ (tc & 7);
            const int p = e >> 1;
            const unsigned sh = (e & 1) << 4;
            const unsigned h0 = (bfp[0][p] >> sh) & 0xFFFFu;
            const unsigned h1 = (bfp[1][p] >> sh) & 0xFFFFu;
            const unsigned h2 = (bfp[2][p] >> sh) & 0xFFFFu;
            const unsigned h3 = (bfp[3][p] >> sh) & 0xFFFFu;
            const int d = tc * 8 + e;
            *(uint2*)&XjT[d * 64 + (((tr >> 1) ^ e) << 3) + ((tr & 1) << 2)] =
                make_uint2(h0 | (h1 << 16), h2 | (h3 << 16));
        }
        __syncthreads();

        #pragma unroll
        for (int jn = 0; jn < 4; ++jn) {
            f32x4 a0 = (f32x4){0.f, 0.f, 0.f, 0.f};
            f32x4 a1 = (f32x4){0.f, 0.f, 0.f, 0.f};
            #pragma unroll
            for (int kk = 0; kk < 4; ++kk) {
                const short8 xj = *(const short8*)&XjRM[(jn * 16 + r16) * 128 +
                                                        (((kk * 4 + q) ^ sw) << 3)];
                a0 = __builtin_amdgcn_mfma_f32_16x16x32_bf16(xj, xi[0][kk], a0, 0, 0, 0);
                a1 = __builtin_amdgcn_mfma_f32_16x16x32_bf16(xj, xi[1][kk], a1, 0, 0, 0);
            }
            const f32x4 sj = *(const f32x4*)&csqj[jn * 16 + q * 4];
            #pragma unroll
            for (int im = 0; im < 2; ++im) {
                const f32x4 a = im ? a1 : a0;
                const float cii = ci[im];
                us4 hv;
                #pragma unroll
                for (int rg = 0; rg < 4; ++rg) {
                    float arg = fmaf(a[rg], c2, -(sj[rg] + cii));
                    arg = fminf(arg, 0.f);
                    const float wval = __builtin_amdgcn_exp2f(arg);
                    hv[rg] = (unsigned short)((__float_as_uint(wval) + 0x8000u) >> 16);
                }
                *(us4*)&Pm[(wv * 32 + im * 16 + r16) * 72 + jn * 16 + q * 4] = hv;
            }
        }

        #pragma unroll
        for (int kk = 0; kk < 2; ++kk) {
            const short8 pf0 = *(const short8*)&Pm[(wv * 32 + r16) * 72 + kk * 32 + q * 8];
            const short8 pf1 = *(const short8*)&Pm[(wv * 32 + 16 + r16) * 72 + kk * 32 + q * 8];
            #pragma unroll
            for (int nt = 0; nt < 8; ++nt) {
                const short8 bf = *(const short8*)&XjT[(nt * 16 + r16) * 64 +
                                                       (((kk * 4 + q) ^ sw) << 3)];
                acc_o[0][nt] = __builtin_amdgcn_mfma_f32_16x16x32_bf16(pf0, bf, acc_o[0][nt], 0, 0, 0);
                acc_o[1][nt] = __builtin_amdgcn_mfma_f32_16x16x32_bf16(pf1, bf, acc_o[1][nt], 0, 0, 0);
            }
        }
    }

    const float sc = 1.0f / 1024.0f;
    #pragma unroll
    for (int im = 0; im < 2; ++im)
        #pragma unroll
        for (int nt = 0; nt < 8; ++nt)
            #pragma unroll
            for (int rg = 0; rg < 4; ++rg) {
                const int row = i0 + wv * 32 + im * 16 + q * 4 + rg;
                out[(size_t)row * DD + nt * 16 + r16] = acc_o[im][nt][rg] * sc;
            }
}

extern "C" void kernel_launch(void* const* d_in, const int* in_sizes, int n_in,
                              void* d_out, int out_size, void* d_ws, size_t ws_size,
                              hipStream_t stream) {
    (void)in_sizes; (void)n_in; (void)out_size;
    const float* x = (const float*)d_in[0];
    float* out = (float*)d_out;

    const size_t XRM_BYTES = (size_t)262144 * 256;        // 67,108,864
    const size_t XT_BYTES  = (size_t)256 * 16 * 16384;    // 67,108,864
    const size_t SQ_BYTES  = (size_t)262144 * 4;          // 1,048,576

    if (ws_size >= XRM_BYTES + XT_BYTES + SQ_BYTES) {
        unsigned short* xrm = (unsigned short*)d_ws;
        unsigned short* xt  = (unsigned short*)((char*)d_ws + XRM_BYTES);
        float*          sq  = (float*)((char*)d_ws + XRM_BYTES + XT_BYTES);
        pass1_convert<<<dim3(4096), dim3(256), 0, stream>>>(x, xrm, xt, sq);
        block_attn_mx<<<dim3(2048), dim3(256), 0, stream>>>(xrm, xt, sq, out);
    } else {
        block_attn_fused<<<dim3(2048), dim3(256), 0, stream>>>(x, out);
    }
}